// Round 9
// baseline (181.704 us; speedup 1.0000x reference)
//
#include <hip/hip_runtime.h>
#include <hip/hip_bf16.h>

typedef unsigned short u16;
typedef unsigned int u32;
typedef __attribute__((ext_vector_type(8))) short short8;
typedef __attribute__((ext_vector_type(4))) float f32x4;
typedef __attribute__((ext_vector_type(4))) u16 us4;

#define MFMA16(a,b,c) __builtin_amdgcn_mfma_f32_16x16x32_bf16(a,b,c,0,0,0)

__device__ __forceinline__ u16 f2b(float x){
  u32 u = __builtin_bit_cast(u32, x);
  u32 r = (u + 0x7fffu + ((u >> 16) & 1u)) >> 16;
  return (u16)r;
}
__device__ __forceinline__ u16 f2b_hw(float x){
  return __builtin_bit_cast(u16, __float2bfloat16(x));
}
__device__ __forceinline__ float ex2(float x){ return __builtin_amdgcn_exp2f(x); }

__device__ __forceinline__ void gll16(const u16* g, u16* l){
  __builtin_amdgcn_global_load_lds((const __attribute__((address_space(1))) u32*)g,
                                   (__attribute__((address_space(3))) u32*)l, 16, 0, 0);
}

// ---------------- fused: f32->bf16 convert (Drift+Ocean) + weight transposes + lambda ----------
// bid < 8192: conv; else prep_w (z = (bid-8192)>>11, 64x32 tile grid per z)
__global__ __launch_bounds__(256) void k_prep(const float* __restrict__ Drift, const float* __restrict__ Ocean,
                                              const float* __restrict__ Wq, const float* __restrict__ Wk,
                                              const float* __restrict__ Wv, const float* __restrict__ Wo,
                                              u16* __restrict__ Xd, u16* __restrict__ Xo,
                                              u16* __restrict__ WqT, u16* __restrict__ WkvT,
                                              u16* __restrict__ WoT,
                                              const float* __restrict__ lq1, const float* __restrict__ lk1,
                                              const float* __restrict__ lq2, const float* __restrict__ lk2,
                                              float* __restrict__ lam){
  __shared__ float t[32][33];
  int bid = blockIdx.x;
  if (bid < 8192){
    const float* x = (bid < 4096) ? Drift : Ocean;
    u16* y = (bid < 4096) ? Xd : Xo;
    int i = (bid & 4095) * 256 + threadIdx.x;
    float4 v = reinterpret_cast<const float4*>(x)[i];
    us4 o; o.x = f2b(v.x); o.y = f2b(v.y); o.z = f2b(v.z); o.w = f2b(v.w);
    reinterpret_cast<us4*>(y)[i] = o;
    return;
  }
  int tt = bid - 8192;
  int z = tt >> 11;
  int bx = tt & 63, by = (tt & 2047) >> 6;
  const float* W; u16* WT; int N; float scale = 1.0f;
  if (z == 0){ W = Wq; WT = WqT; N = 2048; scale = 0.1803368867f; }   // 0.125 * log2(e)
  else if (z == 1){ W = Wk; WT = WkvT; N = 2048; }
  else if (z == 2){ W = Wv; WT = WkvT + 2048*1024; N = 1024; }
  else { W = Wo; WT = WoT; N = 1024; }
  int n0 = bx * 32, k0 = by * 32;
  int tx = threadIdx.x & 31, ty = threadIdx.x >> 5;
  if (n0 < N){
    #pragma unroll
    for (int i = 0; i < 4; i++)
      t[ty + i*8][tx] = W[(size_t)(k0 + ty + i*8) * N + n0 + tx];
    __syncthreads();
    #pragma unroll
    for (int i = 0; i < 4; i++)
      WT[(size_t)(n0 + ty + i*8) * 1024 + k0 + tx] = f2b(t[tx][ty + i*8] * scale);
  }
  if (z == 3 && bx == 0 && by == 0 && threadIdx.x < 16){
    int h = threadIdx.x;
    float d1 = 0.f, d2 = 0.f;
    for (int i = 0; i < 64; i++){
      d1 += lq1[h*64 + i] * lk1[h*64 + i];
      d2 += lq2[h*64 + i] * lk2[h*64 + i];
    }
    lam[h] = expf(d1) - expf(d2) + 0.1f;
  }
}

// ---------------- V slice of KVb -> VT [64 bh][64 d][1024 kv] bf16 ----------------
__global__ __launch_bounds__(256) void k_transpose_v(const u16* __restrict__ KV, u16* __restrict__ VT){
  __shared__ u16 t[32][34];
  int kv0 = blockIdx.x * 32, d0 = blockIdx.y * 32, bh = blockIdx.z;
  int b = bh >> 4, h = bh & 15;
  int tx = threadIdx.x & 31, ty = threadIdx.x >> 5;
  #pragma unroll
  for (int i = 0; i < 4; i++)
    t[ty + i*8][tx] = KV[(size_t)(b*1024 + kv0 + ty + i*8) * 3072 + 2048 + h*64 + d0 + tx];
  __syncthreads();
  #pragma unroll
  for (int i = 0; i < 4; i++)
    VT[(size_t)bh * 65536 + (size_t)(d0 + ty + i*8) * 1024 + kv0 + tx] = t[tx][ty + i*8];
}

// ---------------- GEMM body (128x128 tile, BK=64, K=1024), hoisted addressing ----------------
template<bool OUTF32>
__device__ __forceinline__ void gemm_body(const u16* __restrict__ A, const u16* __restrict__ B,
                                          void* __restrict__ C, int N, int m0, int n0,
                                          u16* As, u16* Bs){
  const int tid = threadIdx.x;
  const int wave = tid >> 6, lane = tid & 63;
  const int lr = lane & 15, lg = lane >> 4;
  const int wm = wave >> 1, wn = wave & 1;
  const int srow = tid >> 3, skc = tid & 7;

  // global staging sources: only +64 per K-step -> incrementing pointers
  const u16* ga[4]; const u16* gb[4];
  #pragma unroll
  for (int c = 0; c < 4; c++){
    int row = c*32 + srow;
    int off = (skc ^ (row & 7)) << 3;
    ga[c] = A + (size_t)(m0 + row) * 1024 + off;
    gb[c] = B + (size_t)(n0 + row) * 1024 + off;
  }
  // LDS fragment bases: row&7 == lr&7, so mt-offset is pure +mt*1024 u16 (imm-foldable)
  const int rba = (wm*64 + lr)*64, rbb = (wn*64 + lr)*64;
  const u16* a0 = As + rba + (((0 + lg) ^ (lr & 7)) << 3);
  const u16* a1 = As + rba + (((4 + lg) ^ (lr & 7)) << 3);
  const u16* b0 = Bs + rbb + (((0 + lg) ^ (lr & 7)) << 3);
  const u16* b1 = Bs + rbb + (((4 + lg) ^ (lr & 7)) << 3);

  f32x4 acc[4][4];
  #pragma unroll
  for (int i = 0; i < 4; i++)
    #pragma unroll
    for (int j = 0; j < 4; j++){ f32x4 z = {0.f,0.f,0.f,0.f}; acc[i][j] = z; }

  u16* asd = As + wave*512;
  u16* bsd = Bs + wave*512;

  for (int t = 0; t < 16; t++){
    #pragma unroll
    for (int c = 0; c < 4; c++){
      gll16(ga[c], asd + c*2048);
      gll16(gb[c], bsd + c*2048);
      ga[c] += 64; gb[c] += 64;
    }
    __syncthreads();
    #pragma unroll
    for (int kc = 0; kc < 2; kc++){
      const u16* ab = kc ? a1 : a0;
      const u16* bb = kc ? b1 : b0;
      short8 af[4], bfr[4];
      #pragma unroll
      for (int mt = 0; mt < 4; mt++)
        af[mt] = *reinterpret_cast<const short8*>(ab + mt*1024);
      #pragma unroll
      for (int nt = 0; nt < 4; nt++)
        bfr[nt] = *reinterpret_cast<const short8*>(bb + nt*1024);
      #pragma unroll
      for (int mt = 0; mt < 4; mt++)
        #pragma unroll
        for (int nt = 0; nt < 4; nt++)
          acc[mt][nt] = MFMA16(af[mt], bfr[nt], acc[mt][nt]);
    }
    __syncthreads();
  }
  #pragma unroll
  for (int mt = 0; mt < 4; mt++)
    #pragma unroll
    for (int nt = 0; nt < 4; nt++)
      #pragma unroll
      for (int r = 0; r < 4; r++){
        int row = m0 + wm*64 + mt*16 + lg*4 + r;
        int col = n0 + wn*64 + nt*16 + lr;
        if (OUTF32) ((float*)C)[(size_t)row * N + col] = acc[mt][nt][r];
        else        ((u16*)C)[(size_t)row * N + col] = f2b_hw(acc[mt][nt][r]);
      }
}

// fused projection GEMM with XCD-chunked swizzle (1280 % 8 == 0, bijective)
__global__ __launch_bounds__(256, 4) void k_gemm_proj(const u16* __restrict__ Xd, const u16* __restrict__ Xo,
                                                      const u16* __restrict__ WqT, const u16* __restrict__ WkvT,
                                                      u16* __restrict__ Qb, u16* __restrict__ KVb){
  __shared__ __align__(16) u16 As[128*64];
  __shared__ __align__(16) u16 Bs[128*64];
  int bid0 = blockIdx.x;
  int bid = (bid0 & 7) * 160 + (bid0 >> 3);
  if (bid < 512){
    gemm_body<false>(Xd, WqT, Qb, 2048, (bid >> 4) * 128, (bid & 15) * 128, As, Bs);
  } else {
    int t = bid - 512;
    gemm_body<false>(Xo, WkvT, KVb, 3072, (t / 24) * 128, (t % 24) * 128, As, Bs);
  }
}

// output GEMM: out = Ob * WoT^T, f32 out
__global__ __launch_bounds__(256, 4) void k_gemm_out(const u16* __restrict__ A, const u16* __restrict__ B,
                                                     float* __restrict__ C){
  __shared__ __align__(16) u16 As[128*64];
  __shared__ __align__(16) u16 Bs[128*64];
  int bid = blockIdx.x;
  gemm_body<true>(A, B, C, 1024, (bid >> 3) * 128, (bid & 7) * 128, As, Bs);
}

// ---------------- no-max softmax on S^T, exp2 domain (lane q = lr) ----------------
__device__ __forceinline__ void softmax_t(f32x4 s[4], float& l, u16* pl, int lr, int lg){
  float sum = 0.f;
  #pragma unroll
  for (int nt = 0; nt < 4; nt++)
    #pragma unroll
    for (int r = 0; r < 4; r++){
      float p = ex2(s[nt][r]);
      s[nt][r] = p;
      sum += p;
    }
  sum += __shfl_xor(sum, 16);
  sum += __shfl_xor(sum, 32);
  l += sum;
  char* base = (char*)pl + lr * 128;
  const int swz = (lr & 7) << 4;
  #pragma unroll
  for (int nt = 0; nt < 4; nt++){
    us4 h;
    h.x = f2b_hw(s[nt][0]); h.y = f2b_hw(s[nt][1]);
    h.z = f2b_hw(s[nt][2]); h.w = f2b_hw(s[nt][3]);
    *reinterpret_cast<us4*>(base + ((nt*32 + lg*8) ^ swz)) = h;
  }
}

// ---------------- differential flash attention: LDS-staged K/V, 128q/block ----------------
__global__ __launch_bounds__(256, 2) void k_attn(const u16* __restrict__ Q, const u16* __restrict__ KVb,
                                                 const u16* __restrict__ VT, const float* __restrict__ lam,
                                                 u16* __restrict__ O){
  int bid = blockIdx.x;
  int logical = (bid & 7) * 64 + (bid >> 3);           // 512 % 8 == 0, bijective
  int qt8 = logical & 7, h = (logical >> 3) & 15, b = logical >> 7;
  const int tid = threadIdx.x, wave = tid >> 6, lane = tid & 63;
  const int lr = lane & 15, lg = lane >> 4;
  const int qb = qt8 * 128 + wave * 32;

  __shared__ __align__(16) u16 Ks[2][8192];            // [buf][64 kv][128 d] chunk-swizzled
  __shared__ __align__(16) u16 Vs[2][4096];            // [buf][64 d][64 kv] chunk-swizzled
  __shared__ __align__(16) u16 Pl[4][2][2][1024];      // [wave][qt][branch][16 q][64 kv]

  const int srow = tid >> 4, schunk = tid & 15;
  const int vrow = tid >> 3, vchunk = tid & 7;
  const u16* Kg = KVb + (size_t)(b*1024 + srow) * 3072 + h*128 + ((schunk ^ (srow & 7)) << 3);
  const u16* Vg = VT + (size_t)(b*16 + h) * 65536 + (size_t)vrow * 1024 + ((vchunk ^ (vrow & 7)) << 3);

  short8 qf[2][2][2];                                  // [branch][qt][kc]
  #pragma unroll
  for (int qt = 0; qt < 2; qt++){
    const u16* Qp = Q + (size_t)(b*1024 + qb + qt*16 + lr) * 2048 + h*128 + lg*8;
    #pragma unroll
    for (int kc = 0; kc < 2; kc++){
      qf[0][qt][kc] = *reinterpret_cast<const short8*>(Qp + kc*32);
      qf[1][qt][kc] = *reinterpret_cast<const short8*>(Qp + 64 + kc*32);
    }
  }
  const float lamh = lam[h];

  f32x4 o[2][4][2];
  #pragma unroll
  for (int br = 0; br < 2; br++)
    #pragma unroll
    for (int nt = 0; nt < 4; nt++)
      #pragma unroll
      for (int qt = 0; qt < 2; qt++){ f32x4 z = {0.f,0.f,0.f,0.f}; o[br][nt][qt] = z; }
  float l[2][2] = {{0.f, 0.f}, {0.f, 0.f}};

  auto STAGE = [&](int buf, int kv0){
    u16* kd = &Ks[buf][tid * 8];
    #pragma unroll
    for (int i = 0; i < 4; i++)
      gll16(Kg + (size_t)(kv0 + i*16) * 3072, kd + i*2048);
    u16* vd = &Vs[buf][tid * 8];
    #pragma unroll
    for (int j = 0; j < 2; j++)
      gll16(Vg + kv0 + (size_t)(j*32) * 1024, vd + j*2048);
  };

  STAGE(0, 0);
  __syncthreads();

  for (int t = 0; t < 16; t++){
    const int cur = t & 1;
    if (t < 15) STAGE(cur ^ 1, (t + 1) << 6);

    const u16* kbuf = &Ks[cur][0];
    const u16* vbuf = &Vs[cur][0];

    #pragma unroll
    for (int br = 0; br < 2; br++){
      short8 kf[4][2];
      #pragma unroll
      for (int nt = 0; nt < 4; nt++)
        #pragma unroll
        for (int kc = 0; kc < 2; kc++)
          kf[nt][kc] = *reinterpret_cast<const short8*>(
              kbuf + (nt*16 + lr)*128 + (((br*8 + kc*4 + lg) ^ (lr & 7)) << 3));
      #pragma unroll
      for (int qt = 0; qt < 2; qt++){
        f32x4 s[4];
        #pragma unroll
        for (int nt = 0; nt < 4; nt++){ f32x4 z = {0.f,0.f,0.f,0.f}; s[nt] = z; }
        __builtin_amdgcn_s_setprio(1);
        #pragma unroll
        for (int nt = 0; nt < 4; nt++)
          #pragma unroll
          for (int kc = 0; kc < 2; kc++)
            s[nt] = MFMA16(kf[nt][kc], qf[br][qt][kc], s[nt]);
        __builtin_amdgcn_s_setprio(0);
        softmax_t(s, l[br][qt], &Pl[wave][qt][br][0], lr, lg);
      }
    }

    const int swz = (lr & 7) << 4;
    __builtin_amdgcn_s_setprio(1);
    #pragma unroll
    for (int kc = 0; kc < 2; kc++){
      short8 pf[2][2];
      #pragma unroll
      for (int qt = 0; qt < 2; qt++)
        #pragma unroll
        for (int br = 0; br < 2; br++)
          pf[qt][br] = *reinterpret_cast<const short8*>(
              (char*)&Pl[wave][qt][br][0] + lr*128 + ((kc*64 + lg*16) ^ swz));
      #pragma unroll
      for (int nt = 0; nt < 4; nt++){
        short8 vf = *reinterpret_cast<const short8*>(
            vbuf + (nt*16 + lr)*64 + (((kc*4 + lg) ^ (lr & 7)) << 3));
        #pragma unroll
        for (int qt = 0; qt < 2; qt++){
          o[0][nt][qt] = MFMA16(vf, pf[qt][0], o[0][nt][qt]);
          o[1][nt][qt] = MFMA16(vf, pf[qt][1], o[1][nt][qt]);
        }
      }
    }
    __builtin_amdgcn_s_setprio(0);
    __syncthreads();
  }

  #pragma unroll
  for (int qt = 0; qt < 2; qt++){
    const float inv1 = 1.0f / l[0][qt];
    const float inv2 = lamh / l[1][qt];
    u16* Op = O + (size_t)(b*1024 + qb + qt*16 + lr) * 1024 + h*64;
    #pragma unroll
    for (int nt = 0; nt < 4; nt++){
      us4 hh;
      #pragma unroll
      for (int r = 0; r < 4; r++){
        float v = o[0][nt][qt][r] * inv1 - o[1][nt][qt][r] * inv2;
        ((u16*)&hh)[r] = f2b_hw(v);
      }
      *reinterpret_cast<us4*>(Op + nt*16 + lg*4) = hh;
    }
  }
}

// ---------------- launch ----------------
extern "C" void kernel_launch(void* const* d_in, const int* in_sizes, int n_in,
                              void* d_out, int out_size, void* d_ws, size_t ws_size,
                              hipStream_t stream){
  const float* Drift = (const float*)d_in[0];
  const float* Ocean = (const float*)d_in[1];
  const float* Wq    = (const float*)d_in[2];
  const float* Wk    = (const float*)d_in[3];
  const float* Wv    = (const float*)d_in[4];
  const float* Wo    = (const float*)d_in[5];
  const float* lq1   = (const float*)d_in[6];
  const float* lk1   = (const float*)d_in[7];
  const float* lq2   = (const float*)d_in[8];
  const float* lk2   = (const float*)d_in[9];
  float* out = (float*)d_out;

  char* ws = (char*)d_ws;
  u16* Xd   = (u16*)(ws);                      // 4096x1024 bf16
  u16* Xo   = (u16*)(ws + 8388608);            // 4096x1024
  u16* WqT  = (u16*)(ws + 16777216);           // 2048x1024
  u16* WkvT = (u16*)(ws + 20971520);           // 3072x1024
  u16* WoT  = (u16*)(ws + 27262976);           // 1024x1024
  u16* Qb   = (u16*)(ws + 29360128);           // 4096x2048
  u16* KVb  = (u16*)(ws + 46137344);           // 4096x3072
  u16* VTb  = (u16*)(ws + 71303168);           // 64x64x1024
  u16* Ob   = (u16*)(ws + 79691776);           // 4096x1024
  float* lam = (float*)(ws + 88080384);        // 16 f32

  k_prep<<<16384, 256, 0, stream>>>(Drift, Ocean, Wq, Wk, Wv, Wo, Xd, Xo,
                                    WqT, WkvT, WoT, lq1, lk1, lq2, lk2, lam);
  k_gemm_proj<<<1280, 256, 0, stream>>>(Xd, Xo, WqT, WkvT, Qb, KVb);
  k_transpose_v<<<dim3(32,2,64), 256, 0, stream>>>(KVb, VTb);
  k_attn<<<512, 256, 0, stream>>>(Qb, KVb, VTb, lam, Ob);
  k_gemm_out<<<256, 256, 0, stream>>>(Ob, WoT, out);
}

// Round 10
// 146.624 us; speedup vs baseline: 1.2392x; 1.2392x over previous
//
#include <hip/hip_runtime.h>
#include <hip/hip_bf16.h>

typedef unsigned short u16;
typedef unsigned int u32;
typedef __attribute__((ext_vector_type(8))) short short8;
typedef __attribute__((ext_vector_type(4))) float f32x4;
typedef __attribute__((ext_vector_type(4))) u16 us4;

#define MFMA16(a,b,c) __builtin_amdgcn_mfma_f32_16x16x32_bf16(a,b,c,0,0,0)

__device__ __forceinline__ u16 f2b(float x){
  u32 u = __builtin_bit_cast(u32, x);
  u32 r = (u + 0x7fffu + ((u >> 16) & 1u)) >> 16;
  return (u16)r;
}
__device__ __forceinline__ u16 f2b_hw(float x){
  return __builtin_bit_cast(u16, __float2bfloat16(x));
}
__device__ __forceinline__ float ex2(float x){ return __builtin_amdgcn_exp2f(x); }

__device__ __forceinline__ void gll16(const u16* g, u16* l){
  __builtin_amdgcn_global_load_lds((const __attribute__((address_space(1))) u32*)g,
                                   (__attribute__((address_space(3))) u32*)l, 16, 0, 0);
}

// ---------------- fused: f32->bf16 convert (Drift+Ocean) + weight transposes + lambda ----------
__global__ __launch_bounds__(256) void k_prep(const float* __restrict__ Drift, const float* __restrict__ Ocean,
                                              const float* __restrict__ Wq, const float* __restrict__ Wk,
                                              const float* __restrict__ Wv, const float* __restrict__ Wo,
                                              u16* __restrict__ Xd, u16* __restrict__ Xo,
                                              u16* __restrict__ WqT, u16* __restrict__ WkvT,
                                              u16* __restrict__ WoT,
                                              const float* __restrict__ lq1, const float* __restrict__ lk1,
                                              const float* __restrict__ lq2, const float* __restrict__ lk2,
                                              float* __restrict__ lam){
  __shared__ float t[32][33];
  int bid = blockIdx.x;
  if (bid < 8192){
    const float* x = (bid < 4096) ? Drift : Ocean;
    u16* y = (bid < 4096) ? Xd : Xo;
    int i = (bid & 4095) * 256 + threadIdx.x;
    float4 v = reinterpret_cast<const float4*>(x)[i];
    us4 o; o.x = f2b(v.x); o.y = f2b(v.y); o.z = f2b(v.z); o.w = f2b(v.w);
    reinterpret_cast<us4*>(y)[i] = o;
    return;
  }
  int tt = bid - 8192;
  int z = tt >> 11;
  int bx = tt & 63, by = (tt & 2047) >> 6;
  const float* W; u16* WT; int N; float scale = 1.0f;
  if (z == 0){ W = Wq; WT = WqT; N = 2048; scale = 0.1803368867f; }   // 0.125 * log2(e)
  else if (z == 1){ W = Wk; WT = WkvT; N = 2048; }
  else if (z == 2){ W = Wv; WT = WkvT + 2048*1024; N = 1024; }
  else { W = Wo; WT = WoT; N = 1024; }
  int n0 = bx * 32, k0 = by * 32;
  int tx = threadIdx.x & 31, ty = threadIdx.x >> 5;
  if (n0 < N){
    #pragma unroll
    for (int i = 0; i < 4; i++)
      t[ty + i*8][tx] = W[(size_t)(k0 + ty + i*8) * N + n0 + tx];
    __syncthreads();
    #pragma unroll
    for (int i = 0; i < 4; i++)
      WT[(size_t)(n0 + ty + i*8) * 1024 + k0 + tx] = f2b(t[tx][ty + i*8] * scale);
  }
  if (z == 3 && bx == 0 && by == 0 && threadIdx.x < 16){
    int h = threadIdx.x;
    float d1 = 0.f, d2 = 0.f;
    for (int i = 0; i < 64; i++){
      d1 += lq1[h*64 + i] * lk1[h*64 + i];
      d2 += lq2[h*64 + i] * lk2[h*64 + i];
    }
    lam[h] = expf(d1) - expf(d2) + 0.1f;
  }
}

// ---------------- V slice of KVb -> VT [64 bh][64 d][1024 kv] bf16 ----------------
__global__ __launch_bounds__(256) void k_transpose_v(const u16* __restrict__ KV, u16* __restrict__ VT){
  __shared__ u16 t[32][34];
  int kv0 = blockIdx.x * 32, d0 = blockIdx.y * 32, bh = blockIdx.z;
  int b = bh >> 4, h = bh & 15;
  int tx = threadIdx.x & 31, ty = threadIdx.x >> 5;
  #pragma unroll
  for (int i = 0; i < 4; i++)
    t[ty + i*8][tx] = KV[(size_t)(b*1024 + kv0 + ty + i*8) * 3072 + 2048 + h*64 + d0 + tx];
  __syncthreads();
  #pragma unroll
  for (int i = 0; i < 4; i++)
    VT[(size_t)bh * 65536 + (size_t)(d0 + ty + i*8) * 1024 + kv0 + tx] = t[tx][ty + i*8];
}

// ---------------- GEMM body (128x128 tile, BK=64, K=1024), hoisted addressing ----------------
// As is padded to 48KB total LDS so at most 3 blocks/CU co-reside (L2-thrash guard, R9 lesson).
template<bool OUTF32>
__device__ __forceinline__ void gemm_body(const u16* __restrict__ A, const u16* __restrict__ B,
                                          void* __restrict__ C, int N, int m0, int n0,
                                          u16* As, u16* Bs){
  const int tid = threadIdx.x;
  const int wave = tid >> 6, lane = tid & 63;
  const int lr = lane & 15, lg = lane >> 4;
  const int wm = wave >> 1, wn = wave & 1;
  const int srow = tid >> 3, skc = tid & 7;

  // global staging sources: only +64 per K-step -> incrementing pointers
  const u16* ga[4]; const u16* gb[4];
  #pragma unroll
  for (int c = 0; c < 4; c++){
    int row = c*32 + srow;
    int off = (skc ^ (row & 7)) << 3;
    ga[c] = A + (size_t)(m0 + row) * 1024 + off;
    gb[c] = B + (size_t)(n0 + row) * 1024 + off;
  }
  // LDS fragment bases: row&7 == lr&7, so mt-offset is pure +mt*1024 u16 (imm-foldable)
  const int rba = (wm*64 + lr)*64, rbb = (wn*64 + lr)*64;
  const u16* a0 = As + rba + (((0 + lg) ^ (lr & 7)) << 3);
  const u16* a1 = As + rba + (((4 + lg) ^ (lr & 7)) << 3);
  const u16* b0 = Bs + rbb + (((0 + lg) ^ (lr & 7)) << 3);
  const u16* b1 = Bs + rbb + (((4 + lg) ^ (lr & 7)) << 3);

  f32x4 acc[4][4];
  #pragma unroll
  for (int i = 0; i < 4; i++)
    #pragma unroll
    for (int j = 0; j < 4; j++){ f32x4 z = {0.f,0.f,0.f,0.f}; acc[i][j] = z; }

  u16* asd = As + wave*512;
  u16* bsd = Bs + wave*512;

  for (int t = 0; t < 16; t++){
    #pragma unroll
    for (int c = 0; c < 4; c++){
      gll16(ga[c], asd + c*2048);
      gll16(gb[c], bsd + c*2048);
      ga[c] += 64; gb[c] += 64;
    }
    __syncthreads();
    #pragma unroll
    for (int kc = 0; kc < 2; kc++){
      const u16* ab = kc ? a1 : a0;
      const u16* bb = kc ? b1 : b0;
      short8 af[4], bfr[4];
      #pragma unroll
      for (int mt = 0; mt < 4; mt++)
        af[mt] = *reinterpret_cast<const short8*>(ab + mt*1024);
      #pragma unroll
      for (int nt = 0; nt < 4; nt++)
        bfr[nt] = *reinterpret_cast<const short8*>(bb + nt*1024);
      #pragma unroll
      for (int mt = 0; mt < 4; mt++)
        #pragma unroll
        for (int nt = 0; nt < 4; nt++)
          acc[mt][nt] = MFMA16(af[mt], bfr[nt], acc[mt][nt]);
    }
    __syncthreads();
  }
  #pragma unroll
  for (int mt = 0; mt < 4; mt++)
    #pragma unroll
    for (int nt = 0; nt < 4; nt++)
      #pragma unroll
      for (int r = 0; r < 4; r++){
        int row = m0 + wm*64 + mt*16 + lg*4 + r;
        int col = n0 + wn*64 + nt*16 + lr;
        if (OUTF32) ((float*)C)[(size_t)row * N + col] = acc[mt][nt][r];
        else        ((u16*)C)[(size_t)row * N + col] = f2b_hw(acc[mt][nt][r]);
      }
}

// fused projection GEMM with XCD-chunked swizzle (1280 % 8 == 0, bijective)
__global__ __launch_bounds__(256) void k_gemm_proj(const u16* __restrict__ Xd, const u16* __restrict__ Xo,
                                                   const u16* __restrict__ WqT, const u16* __restrict__ WkvT,
                                                   u16* __restrict__ Qb, u16* __restrict__ KVb){
  __shared__ __align__(16) u16 As[128*64 + 8192];   // +16KB pad -> 48KB/block -> <=3 blocks/CU
  __shared__ __align__(16) u16 Bs[128*64];
  int bid0 = blockIdx.x;
  int bid = (bid0 & 7) * 160 + (bid0 >> 3);
  if (bid < 512){
    gemm_body<false>(Xd, WqT, Qb, 2048, (bid >> 4) * 128, (bid & 15) * 128, As, Bs);
  } else {
    int t = bid - 512;
    gemm_body<false>(Xo, WkvT, KVb, 3072, (t / 24) * 128, (t % 24) * 128, As, Bs);
  }
}

// output GEMM: out = Ob * WoT^T, f32 out
__global__ __launch_bounds__(256) void k_gemm_out(const u16* __restrict__ A, const u16* __restrict__ B,
                                                  float* __restrict__ C){
  __shared__ __align__(16) u16 As[128*64 + 8192];   // same 48KB guard
  __shared__ __align__(16) u16 Bs[128*64];
  int bid = blockIdx.x;
  gemm_body<true>(A, B, C, 1024, (bid >> 3) * 128, (bid & 7) * 128, As, Bs);
}

// ---------------- no-max softmax on S^T, exp2 domain (lane q = lr) ----------------
__device__ __forceinline__ void softmax_t(f32x4 s[4], float& l, u16* pl, int lr, int lg){
  float sum = 0.f;
  #pragma unroll
  for (int nt = 0; nt < 4; nt++)
    #pragma unroll
    for (int r = 0; r < 4; r++){
      float p = ex2(s[nt][r]);
      s[nt][r] = p;
      sum += p;
    }
  sum += __shfl_xor(sum, 16);
  sum += __shfl_xor(sum, 32);
  l += sum;
  char* base = (char*)pl + lr * 128;
  const int swz = (lr & 7) << 4;
  #pragma unroll
  for (int nt = 0; nt < 4; nt++){
    us4 h;
    h.x = f2b_hw(s[nt][0]); h.y = f2b_hw(s[nt][1]);
    h.z = f2b_hw(s[nt][2]); h.w = f2b_hw(s[nt][3]);
    *reinterpret_cast<us4*>(base + ((nt*32 + lg*8) ^ swz)) = h;
  }
}

// ---------------- differential flash attention: LDS-staged K/V, 128q/block ----------------
__global__ __launch_bounds__(256, 2) void k_attn(const u16* __restrict__ Q, const u16* __restrict__ KVb,
                                                 const u16* __restrict__ VT, const float* __restrict__ lam,
                                                 u16* __restrict__ O){
  int bid = blockIdx.x;
  int logical = (bid & 7) * 64 + (bid >> 3);           // 512 % 8 == 0, bijective
  int qt8 = logical & 7, h = (logical >> 3) & 15, b = logical >> 7;
  const int tid = threadIdx.x, wave = tid >> 6, lane = tid & 63;
  const int lr = lane & 15, lg = lane >> 4;
  const int qb = qt8 * 128 + wave * 32;

  __shared__ __align__(16) u16 Ks[2][8192];            // [buf][64 kv][128 d] chunk-swizzled
  __shared__ __align__(16) u16 Vs[2][4096];            // [buf][64 d][64 kv] chunk-swizzled
  __shared__ __align__(16) u16 Pl[4][2][2][1024];      // [wave][qt][branch][16 q][64 kv]

  const int srow = tid >> 4, schunk = tid & 15;
  const int vrow = tid >> 3, vchunk = tid & 7;
  const u16* Kg = KVb + (size_t)(b*1024 + srow) * 3072 + h*128 + ((schunk ^ (srow & 7)) << 3);
  const u16* Vg = VT + (size_t)(b*16 + h) * 65536 + (size_t)vrow * 1024 + ((vchunk ^ (vrow & 7)) << 3);

  short8 qf[2][2][2];                                  // [branch][qt][kc]
  #pragma unroll
  for (int qt = 0; qt < 2; qt++){
    const u16* Qp = Q + (size_t)(b*1024 + qb + qt*16 + lr) * 2048 + h*128 + lg*8;
    #pragma unroll
    for (int kc = 0; kc < 2; kc++){
      qf[0][qt][kc] = *reinterpret_cast<const short8*>(Qp + kc*32);
      qf[1][qt][kc] = *reinterpret_cast<const short8*>(Qp + 64 + kc*32);
    }
  }
  const float lamh = lam[h];

  f32x4 o[2][4][2];
  #pragma unroll
  for (int br = 0; br < 2; br++)
    #pragma unroll
    for (int nt = 0; nt < 4; nt++)
      #pragma unroll
      for (int qt = 0; qt < 2; qt++){ f32x4 z = {0.f,0.f,0.f,0.f}; o[br][nt][qt] = z; }
  float l[2][2] = {{0.f, 0.f}, {0.f, 0.f}};

  auto STAGE = [&](int buf, int kv0){
    u16* kd = &Ks[buf][tid * 8];
    #pragma unroll
    for (int i = 0; i < 4; i++)
      gll16(Kg + (size_t)(kv0 + i*16) * 3072, kd + i*2048);
    u16* vd = &Vs[buf][tid * 8];
    #pragma unroll
    for (int j = 0; j < 2; j++)
      gll16(Vg + kv0 + (size_t)(j*32) * 1024, vd + j*2048);
  };

  STAGE(0, 0);
  __syncthreads();

  for (int t = 0; t < 16; t++){
    const int cur = t & 1;
    if (t < 15) STAGE(cur ^ 1, (t + 1) << 6);

    const u16* kbuf = &Ks[cur][0];
    const u16* vbuf = &Vs[cur][0];

    #pragma unroll
    for (int br = 0; br < 2; br++){
      short8 kf[4][2];
      #pragma unroll
      for (int nt = 0; nt < 4; nt++)
        #pragma unroll
        for (int kc = 0; kc < 2; kc++)
          kf[nt][kc] = *reinterpret_cast<const short8*>(
              kbuf + (nt*16 + lr)*128 + (((br*8 + kc*4 + lg) ^ (lr & 7)) << 3));
      #pragma unroll
      for (int qt = 0; qt < 2; qt++){
        f32x4 s[4];
        #pragma unroll
        for (int nt = 0; nt < 4; nt++){ f32x4 z = {0.f,0.f,0.f,0.f}; s[nt] = z; }
        __builtin_amdgcn_s_setprio(1);
        #pragma unroll
        for (int nt = 0; nt < 4; nt++)
          #pragma unroll
          for (int kc = 0; kc < 2; kc++)
            s[nt] = MFMA16(kf[nt][kc], qf[br][qt][kc], s[nt]);
        __builtin_amdgcn_s_setprio(0);
        softmax_t(s, l[br][qt], &Pl[wave][qt][br][0], lr, lg);
      }
    }

    const int swz = (lr & 7) << 4;
    __builtin_amdgcn_s_setprio(1);
    #pragma unroll
    for (int kc = 0; kc < 2; kc++){
      short8 pf[2][2];
      #pragma unroll
      for (int qt = 0; qt < 2; qt++)
        #pragma unroll
        for (int br = 0; br < 2; br++)
          pf[qt][br] = *reinterpret_cast<const short8*>(
              (char*)&Pl[wave][qt][br][0] + lr*128 + ((kc*64 + lg*16) ^ swz));
      #pragma unroll
      for (int nt = 0; nt < 4; nt++){
        short8 vf = *reinterpret_cast<const short8*>(
            vbuf + (nt*16 + lr)*64 + (((kc*4 + lg) ^ (lr & 7)) << 3));
        #pragma unroll
        for (int qt = 0; qt < 2; qt++){
          o[0][nt][qt] = MFMA16(vf, pf[qt][0], o[0][nt][qt]);
          o[1][nt][qt] = MFMA16(vf, pf[qt][1], o[1][nt][qt]);
        }
      }
    }
    __builtin_amdgcn_s_setprio(0);
    __syncthreads();
  }

  #pragma unroll
  for (int qt = 0; qt < 2; qt++){
    const float inv1 = 1.0f / l[0][qt];
    const float inv2 = lamh / l[1][qt];
    u16* Op = O + (size_t)(b*1024 + qb + qt*16 + lr) * 1024 + h*64;
    #pragma unroll
    for (int nt = 0; nt < 4; nt++){
      us4 hh;
      #pragma unroll
      for (int r = 0; r < 4; r++){
        float v = o[0][nt][qt][r] * inv1 - o[1][nt][qt][r] * inv2;
        ((u16*)&hh)[r] = f2b_hw(v);
      }
      *reinterpret_cast<us4*>(Op + nt*16 + lg*4) = hh;
    }
  }
}

// ---------------- launch ----------------
extern "C" void kernel_launch(void* const* d_in, const int* in_sizes, int n_in,
                              void* d_out, int out_size, void* d_ws, size_t ws_size,
                              hipStream_t stream){
  const float* Drift = (const float*)d_in[0];
  const float* Ocean = (const float*)d_in[1];
  const float* Wq    = (const float*)d_in[2];
  const float* Wk    = (const float*)d_in[3];
  const float* Wv    = (const float*)d_in[4];
  const float* Wo    = (const float*)d_in[5];
  const float* lq1   = (const float*)d_in[6];
  const float* lk1   = (const float*)d_in[7];
  const float* lq2   = (const float*)d_in[8];
  const float* lk2   = (const float*)d_in[9];
  float* out = (float*)d_out;

  char* ws = (char*)d_ws;
  u16* Xd   = (u16*)(ws);                      // 4096x1024 bf16
  u16* Xo   = (u16*)(ws + 8388608);            // 4096x1024
  u16* WqT  = (u16*)(ws + 16777216);           // 2048x1024
  u16* WkvT = (u16*)(ws + 20971520);           // 3072x1024
  u16* WoT  = (u16*)(ws + 27262976);           // 1024x1024
  u16* Qb   = (u16*)(ws + 29360128);           // 4096x2048
  u16* KVb  = (u16*)(ws + 46137344);           // 4096x3072
  u16* VTb  = (u16*)(ws + 71303168);           // 64x64x1024
  u16* Ob   = (u16*)(ws + 79691776);           // 4096x1024
  float* lam = (float*)(ws + 88080384);        // 16 f32

  k_prep<<<16384, 256, 0, stream>>>(Drift, Ocean, Wq, Wk, Wv, Wo, Xd, Xo,
                                    WqT, WkvT, WoT, lq1, lk1, lq2, lk2, lam);
  k_gemm_proj<<<1280, 256, 0, stream>>>(Xd, Xo, WqT, WkvT, Qb, KVb);
  k_transpose_v<<<dim3(32,2,64), 256, 0, stream>>>(KVb, VTb);
  k_attn<<<512, 256, 0, stream>>>(Qb, KVb, VTb, lam, Ob);
  k_gemm_out<<<256, 256, 0, stream>>>(Ob, WoT, out);
}

// Round 11
// 143.184 us; speedup vs baseline: 1.2690x; 1.0240x over previous
//
#include <hip/hip_runtime.h>
#include <hip/hip_bf16.h>

typedef unsigned short u16;
typedef unsigned int u32;
typedef __attribute__((ext_vector_type(8))) short short8;
typedef __attribute__((ext_vector_type(4))) float f32x4;
typedef __attribute__((ext_vector_type(4))) u16 us4;

#define MFMA16(a,b,c) __builtin_amdgcn_mfma_f32_16x16x32_bf16(a,b,c,0,0,0)

__device__ __forceinline__ u16 f2b(float x){
  u32 u = __builtin_bit_cast(u32, x);
  u32 r = (u + 0x7fffu + ((u >> 16) & 1u)) >> 16;
  return (u16)r;
}
__device__ __forceinline__ u16 f2b_hw(float x){
  return __builtin_bit_cast(u16, __float2bfloat16(x));
}
__device__ __forceinline__ float ex2(float x){ return __builtin_amdgcn_exp2f(x); }

__device__ __forceinline__ void gll16(const u16* g, u16* l){
  __builtin_amdgcn_global_load_lds((const __attribute__((address_space(1))) u32*)g,
                                   (__attribute__((address_space(3))) u32*)l, 16, 0, 0);
}

// ---------------- fused: f32->bf16 convert (Drift+Ocean) + weight transposes + lambda ----------
__global__ __launch_bounds__(256) void k_prep(const float* __restrict__ Drift, const float* __restrict__ Ocean,
                                              const float* __restrict__ Wq, const float* __restrict__ Wk,
                                              const float* __restrict__ Wv, const float* __restrict__ Wo,
                                              u16* __restrict__ Xd, u16* __restrict__ Xo,
                                              u16* __restrict__ WqT, u16* __restrict__ WkvT,
                                              u16* __restrict__ WoT,
                                              const float* __restrict__ lq1, const float* __restrict__ lk1,
                                              const float* __restrict__ lq2, const float* __restrict__ lk2,
                                              float* __restrict__ lam){
  __shared__ float t[32][33];
  int bid = blockIdx.x;
  if (bid < 8192){
    const float* x = (bid < 4096) ? Drift : Ocean;
    u16* y = (bid < 4096) ? Xd : Xo;
    int i = (bid & 4095) * 256 + threadIdx.x;
    float4 v = reinterpret_cast<const float4*>(x)[i];
    us4 o; o.x = f2b(v.x); o.y = f2b(v.y); o.z = f2b(v.z); o.w = f2b(v.w);
    reinterpret_cast<us4*>(y)[i] = o;
    return;
  }
  int tt = bid - 8192;
  int z = tt >> 11;
  int bx = tt & 63, by = (tt & 2047) >> 6;
  const float* W; u16* WT; int N; float scale = 1.0f;
  if (z == 0){ W = Wq; WT = WqT; N = 2048; scale = 0.1803368867f; }   // 0.125 * log2(e)
  else if (z == 1){ W = Wk; WT = WkvT; N = 2048; }
  else if (z == 2){ W = Wv; WT = WkvT + 2048*1024; N = 1024; }
  else { W = Wo; WT = WoT; N = 1024; }
  int n0 = bx * 32, k0 = by * 32;
  int tx = threadIdx.x & 31, ty = threadIdx.x >> 5;
  if (n0 < N){
    #pragma unroll
    for (int i = 0; i < 4; i++)
      t[ty + i*8][tx] = W[(size_t)(k0 + ty + i*8) * N + n0 + tx];
    __syncthreads();
    #pragma unroll
    for (int i = 0; i < 4; i++)
      WT[(size_t)(n0 + ty + i*8) * 1024 + k0 + tx] = f2b(t[tx][ty + i*8] * scale);
  }
  if (z == 3 && bx == 0 && by == 0 && threadIdx.x < 16){
    int h = threadIdx.x;
    float d1 = 0.f, d2 = 0.f;
    for (int i = 0; i < 64; i++){
      d1 += lq1[h*64 + i] * lk1[h*64 + i];
      d2 += lq2[h*64 + i] * lk2[h*64 + i];
    }
    lam[h] = expf(d1) - expf(d2) + 0.1f;
  }
}

// ---------------- V slice of KVb -> VT [64 bh][64 d][1024 kv] bf16 ----------------
__global__ __launch_bounds__(256) void k_transpose_v(const u16* __restrict__ KV, u16* __restrict__ VT){
  __shared__ u16 t[32][34];
  int kv0 = blockIdx.x * 32, d0 = blockIdx.y * 32, bh = blockIdx.z;
  int b = bh >> 4, h = bh & 15;
  int tx = threadIdx.x & 31, ty = threadIdx.x >> 5;
  #pragma unroll
  for (int i = 0; i < 4; i++)
    t[ty + i*8][tx] = KV[(size_t)(b*1024 + kv0 + ty + i*8) * 3072 + 2048 + h*64 + d0 + tx];
  __syncthreads();
  #pragma unroll
  for (int i = 0; i < 4; i++)
    VT[(size_t)bh * 65536 + (size_t)(d0 + ty + i*8) * 1024 + kv0 + tx] = t[tx][ty + i*8];
}

// ---------------- GEMM body (128x128 tile, BK=64, K=1024) — R8-proven structure ----------------
template<bool OUTF32>
__device__ __forceinline__ void gemm_body(const u16* __restrict__ A, const u16* __restrict__ B,
                                          void* __restrict__ C, int N, int m0, int n0,
                                          u16* As, u16* Bs){
  const int tid = threadIdx.x;
  const int wave = tid >> 6, lane = tid & 63;
  const int lr = lane & 15, lg = lane >> 4;
  const int wm = wave >> 1, wn = wave & 1;

  f32x4 acc[4][4];
  #pragma unroll
  for (int i = 0; i < 4; i++)
    #pragma unroll
    for (int j = 0; j < 4; j++){ f32x4 z = {0.f,0.f,0.f,0.f}; acc[i][j] = z; }

  const int srow = tid >> 3;
  const int skc  = tid & 7;

  for (int k0 = 0; k0 < 1024; k0 += 64){
    #pragma unroll
    for (int c = 0; c < 4; c++){
      int row = c*32 + srow;
      const u16* ga = A + (size_t)(m0 + row) * 1024 + k0 + ((skc ^ (row & 7)) << 3);
      gll16(ga, As + c*2048 + wave*512);
      const u16* gb = B + (size_t)(n0 + row) * 1024 + k0 + ((skc ^ (row & 7)) << 3);
      gll16(gb, Bs + c*2048 + wave*512);
    }
    __syncthreads();
    #pragma unroll
    for (int kc = 0; kc < 2; kc++){
      short8 af[4], bfr[4];
      #pragma unroll
      for (int mt = 0; mt < 4; mt++){
        int row = wm*64 + mt*16 + lr;
        af[mt] = *reinterpret_cast<const short8*>(As + row*64 + (((kc*4 + lg) ^ (row & 7)) << 3));
      }
      #pragma unroll
      for (int nt = 0; nt < 4; nt++){
        int rown = wn*64 + nt*16 + lr;
        bfr[nt] = *reinterpret_cast<const short8*>(Bs + rown*64 + (((kc*4 + lg) ^ (rown & 7)) << 3));
      }
      #pragma unroll
      for (int mt = 0; mt < 4; mt++)
        #pragma unroll
        for (int nt = 0; nt < 4; nt++)
          acc[mt][nt] = MFMA16(af[mt], bfr[nt], acc[mt][nt]);
    }
    __syncthreads();
  }
  #pragma unroll
  for (int mt = 0; mt < 4; mt++)
    #pragma unroll
    for (int nt = 0; nt < 4; nt++)
      #pragma unroll
      for (int r = 0; r < 4; r++){
        int row = m0 + wm*64 + mt*16 + lg*4 + r;
        int col = n0 + wn*64 + nt*16 + lr;
        if (OUTF32) ((float*)C)[(size_t)row * N + col] = acc[mt][nt][r];
        else        ((u16*)C)[(size_t)row * N + col] = f2b(acc[mt][nt][r]);
      }
}

// fused projection GEMM with XCD-chunked swizzle (1280 % 8 == 0, bijective)
__global__ __launch_bounds__(256) void k_gemm_proj(const u16* __restrict__ Xd, const u16* __restrict__ Xo,
                                                   const u16* __restrict__ WqT, const u16* __restrict__ WkvT,
                                                   u16* __restrict__ Qb, u16* __restrict__ KVb){
  __shared__ __align__(16) u16 As[128*64];
  __shared__ __align__(16) u16 Bs[128*64];
  int bid0 = blockIdx.x;
  int bid = (bid0 & 7) * 160 + (bid0 >> 3);
  if (bid < 512){
    gemm_body<false>(Xd, WqT, Qb, 2048, (bid >> 4) * 128, (bid & 15) * 128, As, Bs);
  } else {
    int t = bid - 512;
    gemm_body<false>(Xo, WkvT, KVb, 3072, (t / 24) * 128, (t % 24) * 128, As, Bs);
  }
}

// output GEMM: out = Ob * WoT^T, f32 out
__global__ __launch_bounds__(256) void k_gemm_out(const u16* __restrict__ A, const u16* __restrict__ B,
                                                  float* __restrict__ C){
  __shared__ __align__(16) u16 As[128*64];
  __shared__ __align__(16) u16 Bs[128*64];
  int bid = blockIdx.x;
  gemm_body<true>(A, B, C, 1024, (bid >> 3) * 128, (bid & 7) * 128, As, Bs);
}

// ---------------- no-max softmax on S^T, exp2 domain (lane q = lr) ----------------
__device__ __forceinline__ void softmax_t(f32x4 s[4], float& l, u16* pl, int lr, int lg){
  float sum = 0.f;
  #pragma unroll
  for (int nt = 0; nt < 4; nt++)
    #pragma unroll
    for (int r = 0; r < 4; r++){
      float p = ex2(s[nt][r]);
      s[nt][r] = p;
      sum += p;
    }
  sum += __shfl_xor(sum, 16);
  sum += __shfl_xor(sum, 32);
  l += sum;
  char* base = (char*)pl + lr * 128;
  const int swz = (lr & 7) << 4;
  #pragma unroll
  for (int nt = 0; nt < 4; nt++){
    us4 h;
    h.x = f2b_hw(s[nt][0]); h.y = f2b_hw(s[nt][1]);
    h.z = f2b_hw(s[nt][2]); h.w = f2b_hw(s[nt][3]);
    *reinterpret_cast<us4*>(base + ((nt*32 + lg*8) ^ swz)) = h;
  }
}

// ---------------- differential flash attention: 8-wave 256q blocks, LDS-staged K/V ----------------
// Grid 256 (= 1 block/CU): 4 q-tiles x 16 h x 4 b, XCD-chunked. One 24KB K/V stage per
// kv-step now feeds 256 q rows (vs 128 before) -> staging traffic per CU halves.
__global__ __launch_bounds__(512) void k_attn(const u16* __restrict__ Q, const u16* __restrict__ KVb,
                                              const u16* __restrict__ VT, const float* __restrict__ lam,
                                              u16* __restrict__ O){
  int bid = blockIdx.x;
  int logical = (bid & 7) * 32 + (bid >> 3);           // 256 % 8 == 0, bijective
  int qt2 = logical & 3, h = (logical >> 2) & 15, b = logical >> 6;
  const int tid = threadIdx.x, wave = tid >> 6, lane = tid & 63;
  const int lr = lane & 15, lg = lane >> 4;
  const int qb = qt2 * 256 + wave * 32;                // wave's 32 q-rows

  __shared__ __align__(16) u16 Ks[2][8192];            // [buf][64 kv][128 d] chunk-swizzled
  __shared__ __align__(16) u16 Vs[2][4096];            // [buf][64 d][64 kv] chunk-swizzled
  __shared__ __align__(16) u16 Pl[8][2][2][1024];      // [wave][qt][branch][16 q][64 kv]

  // staging: 512 threads. K tile 16KB -> 2 issues (32 rows each); V tile 8KB -> 1 issue.
  const int srow = tid >> 4, schunk = tid & 15;        // K: rows 0..31 per issue
  const int vrow = tid >> 3, vchunk = tid & 7;         // V: rows 0..63
  const u16* Kg = KVb + (size_t)(b*1024 + srow) * 3072 + h*128 + ((schunk ^ (srow & 7)) << 3);
  const u16* Vg = VT + (size_t)(b*16 + h) * 65536 + (size_t)vrow * 1024 + ((vchunk ^ (vrow & 7)) << 3);

  short8 qf[2][2][2];                                  // [branch][qt][kc]
  #pragma unroll
  for (int qt = 0; qt < 2; qt++){
    const u16* Qp = Q + (size_t)(b*1024 + qb + qt*16 + lr) * 2048 + h*128 + lg*8;
    #pragma unroll
    for (int kc = 0; kc < 2; kc++){
      qf[0][qt][kc] = *reinterpret_cast<const short8*>(Qp + kc*32);
      qf[1][qt][kc] = *reinterpret_cast<const short8*>(Qp + 64 + kc*32);
    }
  }
  const float lamh = lam[h];

  f32x4 o[2][4][2];
  #pragma unroll
  for (int br = 0; br < 2; br++)
    #pragma unroll
    for (int nt = 0; nt < 4; nt++)
      #pragma unroll
      for (int qt = 0; qt < 2; qt++){ f32x4 z = {0.f,0.f,0.f,0.f}; o[br][nt][qt] = z; }
  float l[2][2] = {{0.f, 0.f}, {0.f, 0.f}};

  auto STAGE = [&](int buf, int kv0){
    #pragma unroll
    for (int i = 0; i < 2; i++)
      gll16(Kg + (size_t)(kv0 + i*32) * 3072, &Ks[buf][i*4096 + tid*8]);
    gll16(Vg + kv0, &Vs[buf][tid*8]);
  };

  STAGE(0, 0);
  __syncthreads();

  for (int t = 0; t < 16; t++){
    const int cur = t & 1;
    if (t < 15) STAGE(cur ^ 1, (t + 1) << 6);

    const u16* kbuf = &Ks[cur][0];
    const u16* vbuf = &Vs[cur][0];

    #pragma unroll
    for (int br = 0; br < 2; br++){
      short8 kf[4][2];
      #pragma unroll
      for (int nt = 0; nt < 4; nt++)
        #pragma unroll
        for (int kc = 0; kc < 2; kc++)
          kf[nt][kc] = *reinterpret_cast<const short8*>(
              kbuf + (nt*16 + lr)*128 + (((br*8 + kc*4 + lg) ^ (lr & 7)) << 3));
      #pragma unroll
      for (int qt = 0; qt < 2; qt++){
        f32x4 s[4];
        #pragma unroll
        for (int nt = 0; nt < 4; nt++){ f32x4 z = {0.f,0.f,0.f,0.f}; s[nt] = z; }
        __builtin_amdgcn_s_setprio(1);
        #pragma unroll
        for (int nt = 0; nt < 4; nt++)
          #pragma unroll
          for (int kc = 0; kc < 2; kc++)
            s[nt] = MFMA16(kf[nt][kc], qf[br][qt][kc], s[nt]);
        __builtin_amdgcn_s_setprio(0);
        softmax_t(s, l[br][qt], &Pl[wave][qt][br][0], lr, lg);
      }
    }

    const int swz = (lr & 7) << 4;
    __builtin_amdgcn_s_setprio(1);
    #pragma unroll
    for (int kc = 0; kc < 2; kc++){
      short8 pf[2][2];
      #pragma unroll
      for (int qt = 0; qt < 2; qt++)
        #pragma unroll
        for (int br = 0; br < 2; br++)
          pf[qt][br] = *reinterpret_cast<const short8*>(
              (char*)&Pl[wave][qt][br][0] + lr*128 + ((kc*64 + lg*16) ^ swz));
      #pragma unroll
      for (int nt = 0; nt < 4; nt++){
        short8 vf = *reinterpret_cast<const short8*>(
            vbuf + (nt*16 + lr)*64 + (((kc*4 + lg) ^ (lr & 7)) << 3));
        #pragma unroll
        for (int qt = 0; qt < 2; qt++){
          o[0][nt][qt] = MFMA16(vf, pf[qt][0], o[0][nt][qt]);
          o[1][nt][qt] = MFMA16(vf, pf[qt][1], o[1][nt][qt]);
        }
      }
    }
    __builtin_amdgcn_s_setprio(0);
    __syncthreads();
  }

  #pragma unroll
  for (int qt = 0; qt < 2; qt++){
    const float inv1 = 1.0f / l[0][qt];
    const float inv2 = lamh / l[1][qt];
    u16* Op = O + (size_t)(b*1024 + qb + qt*16 + lr) * 1024 + h*64;
    #pragma unroll
    for (int nt = 0; nt < 4; nt++){
      us4 hh;
      #pragma unroll
      for (int r = 0; r < 4; r++){
        float v = o[0][nt][qt][r] * inv1 - o[1][nt][qt][r] * inv2;
        ((u16*)&hh)[r] = f2b_hw(v);
      }
      *reinterpret_cast<us4*>(Op + nt*16 + lg*4) = hh;
    }
  }
}

// ---------------- launch ----------------
extern "C" void kernel_launch(void* const* d_in, const int* in_sizes, int n_in,
                              void* d_out, int out_size, void* d_ws, size_t ws_size,
                              hipStream_t stream){
  const float* Drift = (const float*)d_in[0];
  const float* Ocean = (const float*)d_in[1];
  const float* Wq    = (const float*)d_in[2];
  const float* Wk    = (const float*)d_in[3];
  const float* Wv    = (const float*)d_in[4];
  const float* Wo    = (const float*)d_in[5];
  const float* lq1   = (const float*)d_in[6];
  const float* lk1   = (const float*)d_in[7];
  const float* lq2   = (const float*)d_in[8];
  const float* lk2   = (const float*)d_in[9];
  float* out = (float*)d_out;

  char* ws = (char*)d_ws;
  u16* Xd   = (u16*)(ws);                      // 4096x1024 bf16
  u16* Xo   = (u16*)(ws + 8388608);            // 4096x1024
  u16* WqT  = (u16*)(ws + 16777216);           // 2048x1024
  u16* WkvT = (u16*)(ws + 20971520);           // 3072x1024
  u16* WoT  = (u16*)(ws + 27262976);           // 1024x1024
  u16* Qb   = (u16*)(ws + 29360128);           // 4096x2048
  u16* KVb  = (u16*)(ws + 46137344);           // 4096x3072
  u16* VTb  = (u16*)(ws + 71303168);           // 64x64x1024
  u16* Ob   = (u16*)(ws + 79691776);           // 4096x1024
  float* lam = (float*)(ws + 88080384);        // 16 f32

  k_prep<<<16384, 256, 0, stream>>>(Drift, Ocean, Wq, Wk, Wv, Wo, Xd, Xo,
                                    WqT, WkvT, WoT, lq1, lk1, lq2, lk2, lam);
  k_gemm_proj<<<1280, 256, 0, stream>>>(Xd, Xo, WqT, WkvT, Qb, KVb);
  k_transpose_v<<<dim3(32,2,64), 256, 0, stream>>>(KVb, VTb);
  k_attn<<<256, 512, 0, stream>>>(Qb, KVb, VTb, lam, Ob);
  k_gemm_out<<<256, 256, 0, stream>>>(Ob, WoT, out);
}

// Round 12
// 141.383 us; speedup vs baseline: 1.2852x; 1.0127x over previous
//
#include <hip/hip_runtime.h>
#include <hip/hip_bf16.h>

typedef unsigned short u16;
typedef unsigned int u32;
typedef __attribute__((ext_vector_type(8))) short short8;
typedef __attribute__((ext_vector_type(4))) float f32x4;
typedef __attribute__((ext_vector_type(4))) u16 us4;

#define MFMA16(a,b,c) __builtin_amdgcn_mfma_f32_16x16x32_bf16(a,b,c,0,0,0)

__device__ __forceinline__ u16 f2b(float x){
  u32 u = __builtin_bit_cast(u32, x);
  u32 r = (u + 0x7fffu + ((u >> 16) & 1u)) >> 16;
  return (u16)r;
}
__device__ __forceinline__ u16 f2b_hw(float x){
  return __builtin_bit_cast(u16, __float2bfloat16(x));
}
__device__ __forceinline__ float ex2(float x){ return __builtin_amdgcn_exp2f(x); }
__device__ __forceinline__ float b2f(u16 v){ return __builtin_bit_cast(float, ((u32)v) << 16); }

__device__ __forceinline__ void gll16(const u16* g, u16* l){
  __builtin_amdgcn_global_load_lds((const __attribute__((address_space(1))) u32*)g,
                                   (__attribute__((address_space(3))) u32*)l, 16, 0, 0);
}

// ---------------- fused: f32->bf16 convert (Drift+Ocean) + weight transposes + lambda ----------
__global__ __launch_bounds__(256) void k_prep(const float* __restrict__ Drift, const float* __restrict__ Ocean,
                                              const float* __restrict__ Wq, const float* __restrict__ Wk,
                                              const float* __restrict__ Wv, const float* __restrict__ Wo,
                                              u16* __restrict__ Xd, u16* __restrict__ Xo,
                                              u16* __restrict__ WqT, u16* __restrict__ WkvT,
                                              u16* __restrict__ WoT,
                                              const float* __restrict__ lq1, const float* __restrict__ lk1,
                                              const float* __restrict__ lq2, const float* __restrict__ lk2,
                                              float* __restrict__ lam){
  __shared__ float t[32][33];
  int bid = blockIdx.x;
  if (bid < 8192){
    const float* x = (bid < 4096) ? Drift : Ocean;
    u16* y = (bid < 4096) ? Xd : Xo;
    int i = (bid & 4095) * 256 + threadIdx.x;
    float4 v = reinterpret_cast<const float4*>(x)[i];
    us4 o; o.x = f2b(v.x); o.y = f2b(v.y); o.z = f2b(v.z); o.w = f2b(v.w);
    reinterpret_cast<us4*>(y)[i] = o;
    return;
  }
  int tt = bid - 8192;
  int z = tt >> 11;
  int bx = tt & 63, by = (tt & 2047) >> 6;
  const float* W; u16* WT; int N; float scale = 1.0f;
  if (z == 0){ W = Wq; WT = WqT; N = 2048; scale = 0.1803368867f; }   // 0.125 * log2(e)
  else if (z == 1){ W = Wk; WT = WkvT; N = 2048; }
  else if (z == 2){ W = Wv; WT = WkvT + 2048*1024; N = 1024; }
  else { W = Wo; WT = WoT; N = 1024; }
  int n0 = bx * 32, k0 = by * 32;
  int tx = threadIdx.x & 31, ty = threadIdx.x >> 5;
  if (n0 < N){
    #pragma unroll
    for (int i = 0; i < 4; i++)
      t[ty + i*8][tx] = W[(size_t)(k0 + ty + i*8) * N + n0 + tx];
    __syncthreads();
    #pragma unroll
    for (int i = 0; i < 4; i++)
      WT[(size_t)(n0 + ty + i*8) * 1024 + k0 + tx] = f2b(t[tx][ty + i*8] * scale);
  }
  if (z == 3 && bx == 0 && by == 0 && threadIdx.x < 16){
    int h = threadIdx.x;
    float d1 = 0.f, d2 = 0.f;
    for (int i = 0; i < 64; i++){
      d1 += lq1[h*64 + i] * lk1[h*64 + i];
      d2 += lq2[h*64 + i] * lk2[h*64 + i];
    }
    lam[h] = expf(d1) - expf(d2) + 0.1f;
  }
}

// ---------------- V slice of KVb -> VT [64 bh][64 d][1024 kv] bf16 ----------------
__global__ __launch_bounds__(256) void k_transpose_v(const u16* __restrict__ KV, u16* __restrict__ VT){
  __shared__ u16 t[32][34];
  int kv0 = blockIdx.x * 32, d0 = blockIdx.y * 32, bh = blockIdx.z;
  int b = bh >> 4, h = bh & 15;
  int tx = threadIdx.x & 31, ty = threadIdx.x >> 5;
  #pragma unroll
  for (int i = 0; i < 4; i++)
    t[ty + i*8][tx] = KV[(size_t)(b*1024 + kv0 + ty + i*8) * 3072 + 2048 + h*64 + d0 + tx];
  __syncthreads();
  #pragma unroll
  for (int i = 0; i < 4; i++)
    VT[(size_t)bh * 65536 + (size_t)(d0 + ty + i*8) * 1024 + kv0 + tx] = t[tx][ty + i*8];
}

// ---------------- GEMM body (128x128 tile, BK=64, K=1024) — R8-proven structure ----------------
template<bool OUTF32>
__device__ __forceinline__ void gemm_body(const u16* __restrict__ A, const u16* __restrict__ B,
                                          void* __restrict__ C, int N, int m0, int n0,
                                          u16* As, u16* Bs){
  const int tid = threadIdx.x;
  const int wave = tid >> 6, lane = tid & 63;
  const int lr = lane & 15, lg = lane >> 4;
  const int wm = wave >> 1, wn = wave & 1;

  f32x4 acc[4][4];
  #pragma unroll
  for (int i = 0; i < 4; i++)
    #pragma unroll
    for (int j = 0; j < 4; j++){ f32x4 z = {0.f,0.f,0.f,0.f}; acc[i][j] = z; }

  const int srow = tid >> 3;
  const int skc  = tid & 7;

  for (int k0 = 0; k0 < 1024; k0 += 64){
    #pragma unroll
    for (int c = 0; c < 4; c++){
      int row = c*32 + srow;
      const u16* ga = A + (size_t)(m0 + row) * 1024 + k0 + ((skc ^ (row & 7)) << 3);
      gll16(ga, As + c*2048 + wave*512);
      const u16* gb = B + (size_t)(n0 + row) * 1024 + k0 + ((skc ^ (row & 7)) << 3);
      gll16(gb, Bs + c*2048 + wave*512);
    }
    __syncthreads();
    #pragma unroll
    for (int kc = 0; kc < 2; kc++){
      short8 af[4], bfr[4];
      #pragma unroll
      for (int mt = 0; mt < 4; mt++){
        int row = wm*64 + mt*16 + lr;
        af[mt] = *reinterpret_cast<const short8*>(As + row*64 + (((kc*4 + lg) ^ (row & 7)) << 3));
      }
      #pragma unroll
      for (int nt = 0; nt < 4; nt++){
        int rown = wn*64 + nt*16 + lr;
        bfr[nt] = *reinterpret_cast<const short8*>(Bs + rown*64 + (((kc*4 + lg) ^ (rown & 7)) << 3));
      }
      #pragma unroll
      for (int mt = 0; mt < 4; mt++)
        #pragma unroll
        for (int nt = 0; nt < 4; nt++)
          acc[mt][nt] = MFMA16(af[mt], bfr[nt], acc[mt][nt]);
    }
    __syncthreads();
  }
  #pragma unroll
  for (int mt = 0; mt < 4; mt++)
    #pragma unroll
    for (int nt = 0; nt < 4; nt++)
      #pragma unroll
      for (int r = 0; r < 4; r++){
        int row = m0 + wm*64 + mt*16 + lg*4 + r;
        int col = n0 + wn*64 + nt*16 + lr;
        if (OUTF32) ((float*)C)[(size_t)row * N + col] = acc[mt][nt][r];
        else        ((u16*)C)[(size_t)row * N + col] = f2b(acc[mt][nt][r]);
      }
}

// fused projection GEMM with XCD-chunked swizzle (1280 % 8 == 0, bijective)
__global__ __launch_bounds__(256) void k_gemm_proj(const u16* __restrict__ Xd, const u16* __restrict__ Xo,
                                                   const u16* __restrict__ WqT, const u16* __restrict__ WkvT,
                                                   u16* __restrict__ Qb, u16* __restrict__ KVb){
  __shared__ __align__(16) u16 As[128*64];
  __shared__ __align__(16) u16 Bs[128*64];
  int bid0 = blockIdx.x;
  int bid = (bid0 & 7) * 160 + (bid0 >> 3);
  if (bid < 512){
    gemm_body<false>(Xd, WqT, Qb, 2048, (bid >> 4) * 128, (bid & 15) * 128, As, Bs);
  } else {
    int t = bid - 512;
    gemm_body<false>(Xo, WkvT, KVb, 3072, (t / 24) * 128, (t % 24) * 128, As, Bs);
  }
}

// output GEMM: out = Ob * WoT^T, f32 out
__global__ __launch_bounds__(256) void k_gemm_out(const u16* __restrict__ A, const u16* __restrict__ B,
                                                  float* __restrict__ C){
  __shared__ __align__(16) u16 As[128*64];
  __shared__ __align__(16) u16 Bs[128*64];
  int bid = blockIdx.x;
  gemm_body<true>(A, B, C, 1024, (bid >> 3) * 128, (bid & 7) * 128, As, Bs);
}

// ---------------- no-max softmax on S^T, exp2 domain (lane q = lr) ----------------
// swzv = (lr ^ (lr>>3)) & 7 : breaks lr/lr+8 write conflict (max 2-way = free).
__device__ __forceinline__ void softmax_t(f32x4 s[4], float& l, u16* pl, int lr, int lg, int swzv){
  float sum = 0.f;
  #pragma unroll
  for (int nt = 0; nt < 4; nt++)
    #pragma unroll
    for (int r = 0; r < 4; r++){
      float p = ex2(s[nt][r]);
      s[nt][r] = p;
      sum += p;
    }
  sum += __shfl_xor(sum, 16);
  sum += __shfl_xor(sum, 32);
  l += sum;
  char* base = (char*)pl + lr * 128;
  #pragma unroll
  for (int nt = 0; nt < 4; nt++){
    us4 h;
    h.x = f2b_hw(s[nt][0]); h.y = f2b_hw(s[nt][1]);
    h.z = f2b_hw(s[nt][2]); h.w = f2b_hw(s[nt][3]);
    *reinterpret_cast<us4*>(base + ((nt*32 + lg*8) ^ (swzv << 4))) = h;
  }
}

// ---------------- differential flash attention: branch-per-wave, 3-buf ring, counted vmcnt ----
// Grid 256 (1 block/CU), 512 threads. Waves 0-3: branch1 over q 0..255 (64 q each);
// waves 4-7: branch2 over the same q. K/V staged in a 3-deep ring; per-step counted
// vmcnt(3) + raw s_barrier (never drain to 0 mid-loop). Branch combine via LDS exchange.
__global__ __launch_bounds__(512) void k_attn(const u16* __restrict__ Q, const u16* __restrict__ KVb,
                                              const u16* __restrict__ VT, const float* __restrict__ lam,
                                              u16* __restrict__ O){
  int bid = blockIdx.x;
  int logical = (bid & 7) * 32 + (bid >> 3);           // 256 % 8 == 0, bijective
  int qt2 = logical & 3, h = (logical >> 2) & 15, b = logical >> 6;
  const int tid = threadIdx.x, wave = tid >> 6, lane = tid & 63;
  const int lr = lane & 15, lg = lane >> 4;
  const int br = wave >> 2, wq = wave & 3;             // branch, q-slot
  const int swzv = (lr ^ (lr >> 3)) & 7;

  __shared__ __align__(16) u16 Ks[3][8192];            // ring [buf][64 kv][128 d] chunk-swizzled
  __shared__ __align__(16) u16 Vs[3][4096];            // ring [buf][64 d][64 kv] chunk-swizzled
  __shared__ __align__(16) u16 Pl[8][4][1024];         // [wave][qt][16 q][64 kv]; reused for combine

  const int srow = tid >> 4, schunk = tid & 15;
  const int vrow = tid >> 3, vchunk = tid & 7;
  const u16* Kg = KVb + (size_t)(b*1024 + srow) * 3072 + h*128 + ((schunk ^ (srow & 7)) << 3);
  const u16* Vg = VT + (size_t)(b*16 + h) * 65536 + (size_t)vrow * 1024 + ((vchunk ^ (vrow & 7)) << 3);

  // Q fragments: this wave's branch only, 4 q-tiles of 16
  short8 qf[4][2];
  #pragma unroll
  for (int qt = 0; qt < 4; qt++){
    const u16* Qp = Q + (size_t)(b*1024 + qt2*256 + wq*64 + qt*16 + lr) * 2048 + h*128 + br*64 + lg*8;
    qf[qt][0] = *reinterpret_cast<const short8*>(Qp);
    qf[qt][1] = *reinterpret_cast<const short8*>(Qp + 32);
  }
  const float lamh = lam[h];

  f32x4 o[4][4];                                       // [nt(d)][qt]
  #pragma unroll
  for (int nt = 0; nt < 4; nt++)
    #pragma unroll
    for (int qt = 0; qt < 4; qt++){ f32x4 z = {0.f,0.f,0.f,0.f}; o[nt][qt] = z; }
  float l[4] = {0.f, 0.f, 0.f, 0.f};

  auto STAGE = [&](int buf, int kv0){
    #pragma unroll
    for (int i = 0; i < 2; i++)
      gll16(Kg + (size_t)(kv0 + i*32) * 3072, &Ks[buf][i*4096 + tid*8]);
    gll16(Vg + kv0, &Vs[buf][tid*8]);
  };

  // prologue: stage tiles 0,1; wait tile0 (3 outstanding = tile1)
  STAGE(0, 0);
  STAGE(1, 64);
  asm volatile("s_waitcnt vmcnt(3)" ::: "memory");
  __builtin_amdgcn_s_barrier();
  __builtin_amdgcn_sched_barrier(0);

  u16* Plw = &Pl[wave][0][0];

  for (int t = 0; t < 16; t++){
    const int cur = t % 3;
    if (t <= 13) STAGE((t + 2) % 3, (t + 2) << 6);     // stage t+2 into free ring slot

    const u16* kbuf = &Ks[cur][0];
    const u16* vbuf = &Vs[cur][0];

    // QK^T (S^T = K·Q^T) for this branch
    short8 kf[4][2];
    #pragma unroll
    for (int nt = 0; nt < 4; nt++)
      #pragma unroll
      for (int kc = 0; kc < 2; kc++)
        kf[nt][kc] = *reinterpret_cast<const short8*>(
            kbuf + (nt*16 + lr)*128 + (((br*8 + kc*4 + lg) ^ (lr & 7)) << 3));
    #pragma unroll
    for (int qt = 0; qt < 4; qt++){
      f32x4 s[4];
      #pragma unroll
      for (int nt = 0; nt < 4; nt++){ f32x4 z = {0.f,0.f,0.f,0.f}; s[nt] = z; }
      __builtin_amdgcn_s_setprio(1);
      #pragma unroll
      for (int nt = 0; nt < 4; nt++)
        #pragma unroll
        for (int kc = 0; kc < 2; kc++)
          s[nt] = MFMA16(kf[nt][kc], qf[qt][kc], s[nt]);
      __builtin_amdgcn_s_setprio(0);
      softmax_t(s, l[qt], Plw + qt*1024, lr, lg, swzv);
    }

    // PV (O^T += V^T·P^T)
    #pragma unroll
    for (int kc = 0; kc < 2; kc++){
      short8 pf[4];
      #pragma unroll
      for (int qt = 0; qt < 4; qt++)
        pf[qt] = *reinterpret_cast<const short8*>(
            (char*)(Plw + qt*1024) + lr*128 + ((kc*64 + lg*16) ^ (swzv << 4)));
      __builtin_amdgcn_s_setprio(1);
      #pragma unroll
      for (int nt = 0; nt < 4; nt++){
        short8 vf = *reinterpret_cast<const short8*>(
            vbuf + (nt*16 + lr)*64 + (((kc*4 + lg) ^ (lr & 7)) << 3));
        #pragma unroll
        for (int qt = 0; qt < 4; qt++)
          o[nt][qt] = MFMA16(vf, pf[qt], o[nt][qt]);
      }
      __builtin_amdgcn_s_setprio(0);
    }

    // counted vmcnt: tile t+1 must be complete; t+2's 3 loads may stay in flight
    if (t <= 13){
      asm volatile("s_waitcnt vmcnt(3)" ::: "memory");
      __builtin_amdgcn_s_barrier();
      __builtin_amdgcn_sched_barrier(0);
    } else if (t == 14){
      asm volatile("s_waitcnt vmcnt(0)" ::: "memory");
      __builtin_amdgcn_s_barrier();
      __builtin_amdgcn_sched_barrier(0);
    }
  }

  // ---- epilogue: branch combine via LDS exchange (reuse Pl) ----
  if (br == 1){
    // write lam/l2-scaled O2^T (bf16) into partner-visible buffer Pl[wave][qt]
    #pragma unroll
    for (int qt = 0; qt < 4; qt++){
      const float inv2 = lamh / l[qt];
      char* base = (char*)(Plw + qt*1024) + lr * 128;
      #pragma unroll
      for (int nt = 0; nt < 4; nt++){
        us4 hh;
        #pragma unroll
        for (int r = 0; r < 4; r++)
          ((u16*)&hh)[r] = f2b_hw(o[nt][qt][r] * inv2);
        *reinterpret_cast<us4*>(base + ((nt*32 + lg*8) ^ (swzv << 4))) = hh;
      }
    }
  }
  __syncthreads();
  if (br == 0){
    u16* Px = &Pl[wave + 4][0][0];                      // partner branch-2 buffer
    #pragma unroll
    for (int qt = 0; qt < 4; qt++){
      const float inv1 = 1.0f / l[qt];
      char* base = (char*)(Px + qt*1024) + lr * 128;
      u16* Op = O + (size_t)(b*1024 + qt2*256 + wq*64 + qt*16 + lr) * 1024 + h*64;
      #pragma unroll
      for (int nt = 0; nt < 4; nt++){
        us4 x = *reinterpret_cast<const us4*>(base + ((nt*32 + lg*8) ^ (swzv << 4)));
        us4 hh;
        #pragma unroll
        for (int r = 0; r < 4; r++){
          float v = o[nt][qt][r] * inv1 - b2f(((const u16*)&x)[r]);
          ((u16*)&hh)[r] = f2b_hw(v);
        }
        *reinterpret_cast<us4*>(Op + nt*16 + lg*4) = hh;
      }
    }
  }
}

// ---------------- launch ----------------
extern "C" void kernel_launch(void* const* d_in, const int* in_sizes, int n_in,
                              void* d_out, int out_size, void* d_ws, size_t ws_size,
                              hipStream_t stream){
  const float* Drift = (const float*)d_in[0];
  const float* Ocean = (const float*)d_in[1];
  const float* Wq    = (const float*)d_in[2];
  const float* Wk    = (const float*)d_in[3];
  const float* Wv    = (const float*)d_in[4];
  const float* Wo    = (const float*)d_in[5];
  const float* lq1   = (const float*)d_in[6];
  const float* lk1   = (const float*)d_in[7];
  const float* lq2   = (const float*)d_in[8];
  const float* lk2   = (const float*)d_in[9];
  float* out = (float*)d_out;

  char* ws = (char*)d_ws;
  u16* Xd   = (u16*)(ws);                      // 4096x1024 bf16
  u16* Xo   = (u16*)(ws + 8388608);            // 4096x1024
  u16* WqT  = (u16*)(ws + 16777216);           // 2048x1024
  u16* WkvT = (u16*)(ws + 20971520);           // 3072x1024
  u16* WoT  = (u16*)(ws + 27262976);           // 1024x1024
  u16* Qb   = (u16*)(ws + 29360128);           // 4096x2048
  u16* KVb  = (u16*)(ws + 46137344);           // 4096x3072
  u16* VTb  = (u16*)(ws + 71303168);           // 64x64x1024
  u16* Ob   = (u16*)(ws + 79691776);           // 4096x1024
  float* lam = (float*)(ws + 88080384);        // 16 f32

  k_prep<<<16384, 256, 0, stream>>>(Drift, Ocean, Wq, Wk, Wv, Wo, Xd, Xo,
                                    WqT, WkvT, WoT, lq1, lk1, lq2, lk2, lam);
  k_gemm_proj<<<1280, 256, 0, stream>>>(Xd, Xo, WqT, WkvT, Qb, KVb);
  k_transpose_v<<<dim3(32,2,64), 256, 0, stream>>>(KVb, VTb);
  k_attn<<<256, 512, 0, stream>>>(Qb, KVb, VTb, lam, Ob);
  k_gemm_out<<<256, 256, 0, stream>>>(Ob, WoT, out);
}